// Round 1
// baseline (932.740 us; speedup 1.0000x reference)
//
#include <hip/hip_runtime.h>
#include <stdint.h>

typedef short  s16x8 __attribute__((ext_vector_type(8)));
typedef ushort u16x8 __attribute__((ext_vector_type(8)));
typedef float  f32x4 __attribute__((ext_vector_type(4)));

constexpr int BB = 4, TT = 2048, CC = 1024, HH = 16, DD = 64;
constexpr int MM = BB * TT;         // 8192
constexpr int N_QKV = 3 * CC;       // 3072
constexpr size_t KSEG = (size_t)MM * CC;   // 8388608
constexpr size_t VSEG = 2 * KSEG;

__device__ __forceinline__ ushort bf16_rne(float f) {
  uint32_t u = __builtin_bit_cast(uint32_t, f);
  u += 0x7fffu + ((u >> 16) & 1u);
  return (ushort)(u >> 16);
}
__device__ __forceinline__ float bf16_to_f32(ushort h) {
  uint32_t u = ((uint32_t)h) << 16;
  return __builtin_bit_cast(float, u);
}
__device__ __forceinline__ void split_hl(float f, ushort &hi, ushort &lo) {
  hi = bf16_rne(f);
  lo = bf16_rne(f - bf16_to_f32(hi));
}
__device__ __forceinline__ f32x4 mfma16(s16x8 a, s16x8 b, f32x4 c) {
  return __builtin_amdgcn_mfma_f32_16x16x32_bf16(a, b, c, 0, 0, 0);
}

// ---------------- split convert: f32 -> bf16 hi/lo ----------------
__global__ void k_convert(const float* __restrict__ src, ushort* __restrict__ hi,
                          ushort* __restrict__ lo, int n8) {
  int i = blockIdx.x * blockDim.x + threadIdx.x;
  if (i >= n8) return;
  float4 a = ((const float4*)src)[2 * i];
  float4 b = ((const float4*)src)[2 * i + 1];
  float f[8] = {a.x, a.y, a.z, a.w, b.x, b.y, b.z, b.w};
  u16x8 h, l;
#pragma unroll
  for (int j = 0; j < 8; j++) { ushort hh, ll; split_hl(f[j], hh, ll); h[j] = hh; l[j] = ll; }
  *(u16x8*)(hi + 8 * (size_t)i) = h;
  *(u16x8*)(lo + 8 * (size_t)i) = l;
}

// ------------- transpose + split: W[K][N] -> T[N][K] bf16 hi/lo -------------
__global__ void k_transpose_split(const float* __restrict__ W, ushort* __restrict__ Th,
                                  ushort* __restrict__ Tl, int K, int N) {
  __shared__ float tile[32][33];
  int nt = blockIdx.x * 32, kt = blockIdx.y * 32;
  int tx = threadIdx.x, ty = threadIdx.y;
#pragma unroll
  for (int i = 0; i < 4; i++)
    tile[ty + i * 8][tx] = W[(size_t)(kt + ty + i * 8) * N + nt + tx];
  __syncthreads();
#pragma unroll
  for (int i = 0; i < 4; i++) {
    int nl = ty + i * 8;
    float f = tile[tx][nl];
    ushort h, l; split_hl(f, h, l);
    size_t o = (size_t)(nt + nl) * K + kt + tx;
    Th[o] = h; Tl[o] = l;
  }
}

// ---------------- GEMM: C[M][N] = A[M][K] * Bt[N][K]^T + bias ----------------
// bf16x3: 3 MFMAs per (hi,lo) operand pair. 128x128 tile, BK=32, 4 waves (2x2 of 64x64).
// MODE 0: QKV epilogue (q -> hi/lo ws, k/v -> d_out f32, (B,H,T,D) layout)
// MODE 1: plain f32 out[m*CC + n]
template<int MODE>
__global__ __launch_bounds__(256) void k_gemm(
    const ushort* __restrict__ Ah, const ushort* __restrict__ Al,
    const ushort* __restrict__ Bth, const ushort* __restrict__ Btl,
    const float* __restrict__ bias, int K,
    float* __restrict__ outF, ushort* __restrict__ q_hi, ushort* __restrict__ q_lo) {
  constexpr int LDK = 40;  // 32 + 8 pad: row stride 80B -> conflict-free ds_read_b128
  __shared__ ushort sAh[128 * LDK], sAl[128 * LDK], sBh[128 * LDK], sBl[128 * LDK];
  const int tid = threadIdx.x;
  const int wave = tid >> 6, lane = tid & 63;
  const int wr = wave >> 1, wc = wave & 1;
  const int lr = lane & 15, lg = lane >> 4;
  const int m0 = blockIdx.y * 128, n0 = blockIdx.x * 128;
  const int srow = tid >> 2;
  const int sk = (tid & 3) * 8;

  f32x4 acc[4][4] = {};

  for (int kt = 0; kt < K; kt += 32) {
#pragma unroll
    for (int p = 0; p < 2; p++) {
      int row = srow + p * 64;
      size_t ga = (size_t)(m0 + row) * K + kt + sk;
      size_t gb = (size_t)(n0 + row) * K + kt + sk;
      *(u16x8*)(sAh + row * LDK + sk) = *(const u16x8*)(Ah + ga);
      *(u16x8*)(sAl + row * LDK + sk) = *(const u16x8*)(Al + ga);
      *(u16x8*)(sBh + row * LDK + sk) = *(const u16x8*)(Bth + gb);
      *(u16x8*)(sBl + row * LDK + sk) = *(const u16x8*)(Btl + gb);
    }
    __syncthreads();
    s16x8 fah[4], fal[4], fbh[4], fbl[4];
#pragma unroll
    for (int i = 0; i < 4; i++) {
      fah[i] = *(const s16x8*)(sAh + (wr * 64 + i * 16 + lr) * LDK + lg * 8);
      fal[i] = *(const s16x8*)(sAl + (wr * 64 + i * 16 + lr) * LDK + lg * 8);
      fbh[i] = *(const s16x8*)(sBh + (wc * 64 + i * 16 + lr) * LDK + lg * 8);
      fbl[i] = *(const s16x8*)(sBl + (wc * 64 + i * 16 + lr) * LDK + lg * 8);
    }
#pragma unroll
    for (int mf = 0; mf < 4; mf++)
#pragma unroll
      for (int nf = 0; nf < 4; nf++) {
        acc[mf][nf] = mfma16(fah[mf], fbh[nf], acc[mf][nf]);
        acc[mf][nf] = mfma16(fah[mf], fbl[nf], acc[mf][nf]);
        acc[mf][nf] = mfma16(fal[mf], fbh[nf], acc[mf][nf]);
      }
    __syncthreads();
  }

#pragma unroll
  for (int mf = 0; mf < 4; mf++) {
#pragma unroll
    for (int nf = 0; nf < 4; nf++) {
      int n = n0 + wc * 64 + nf * 16 + lr;
      float bv = bias[n];
#pragma unroll
      for (int r = 0; r < 4; r++) {
        int m = m0 + wr * 64 + mf * 16 + lg * 4 + r;
        float v = acc[mf][nf][r] + bv;
        if constexpr (MODE == 0) {
          int b = m >> 11, t = m & 2047;
          int seg = n >> 10, nn = n & 1023;
          int h = nn >> 6, d = nn & 63;
          size_t idx = ((size_t)((b * 16 + h) * 2048 + t)) * 64 + d;
          if (seg == 0) { ushort hh, ll; split_hl(v, hh, ll); q_hi[idx] = hh; q_lo[idx] = ll; }
          else if (seg == 1) outF[KSEG + idx] = v;
          else outF[VSEG + idx] = v;
        } else {
          outF[(size_t)m * CC + n] = v;
        }
      }
    }
  }
}

// ---------------- flash attention (causal) ----------------
// grid: (T/64 q-tiles, B*H). 4 waves x 16 q-rows. KV tiles of 64.
__global__ __launch_bounds__(256) void k_attn(
    const ushort* __restrict__ q_hi, const ushort* __restrict__ q_lo,
    const float* __restrict__ kf, const float* __restrict__ vf,
    ushort* __restrict__ att_hi, ushort* __restrict__ att_lo) {
  constexpr int LD = 72;  // 64 + 8 pad
  __shared__ ushort sKh[64 * LD], sKl[64 * LD];
  __shared__ ushort sVh[64 * LD], sVl[64 * LD];  // transposed: [d][kv]
  __shared__ ushort sPh[4][16 * LD], sPl[4][16 * LD];
  const int tid = threadIdx.x, wave = tid >> 6, lane = tid & 63;
  const int lr = lane & 15, lg = lane >> 4;
  const int qt = blockIdx.x, bh = blockIdx.y;
  const int qrow = qt * 64 + wave * 16;

  // hoist Q fragments (reused across all kv tiles)
  s16x8 fqh[2], fql[2];
  {
    size_t qb = ((size_t)bh * TT + qrow + lr) * 64;
#pragma unroll
    for (int ks = 0; ks < 2; ks++) {
      fqh[ks] = *(const s16x8*)(q_hi + qb + ks * 32 + lg * 8);
      fql[ks] = *(const s16x8*)(q_lo + qb + ks * 32 + lg * 8);
    }
  }
  float mrun[4], lrun[4];
#pragma unroll
  for (int r = 0; r < 4; r++) { mrun[r] = -INFINITY; lrun[r] = 0.f; }
  f32x4 oacc[4] = {};

  const int strow = tid >> 2;
  const int stcol = (tid & 3) * 16;

  for (int kt = 0; kt <= qt; kt++) {
    {  // stage K row-major, V transposed, f32 -> bf16 hi/lo
      size_t gb = ((size_t)bh * TT + kt * 64 + strow) * 64 + stcol;
#pragma unroll
      for (int hf = 0; hf < 2; hf++) {
        float fk[8], fv[8];
        *(float4*)(fk)     = *(const float4*)(kf + gb + hf * 8);
        *(float4*)(fk + 4) = *(const float4*)(kf + gb + hf * 8 + 4);
        *(float4*)(fv)     = *(const float4*)(vf + gb + hf * 8);
        *(float4*)(fv + 4) = *(const float4*)(vf + gb + hf * 8 + 4);
        u16x8 kh, kl;
#pragma unroll
        for (int j = 0; j < 8; j++) {
          ushort h, l; split_hl(fk[j], h, l); kh[j] = h; kl[j] = l;
          ushort vh2, vl2; split_hl(fv[j], vh2, vl2);
          sVh[(stcol + hf * 8 + j) * LD + strow] = vh2;
          sVl[(stcol + hf * 8 + j) * LD + strow] = vl2;
        }
        *(u16x8*)(sKh + strow * LD + stcol + hf * 8) = kh;
        *(u16x8*)(sKl + strow * LD + stcol + hf * 8) = kl;
      }
    }
    __syncthreads();

    // S = Q K^T (bf16x3)
    f32x4 sa[4];
#pragma unroll
    for (int nf = 0; nf < 4; nf++) {
      f32x4 a = {};
#pragma unroll
      for (int ks = 0; ks < 2; ks++) {
        s16x8 kbh = *(const s16x8*)(sKh + (nf * 16 + lr) * LD + ks * 32 + lg * 8);
        s16x8 kbl = *(const s16x8*)(sKl + (nf * 16 + lr) * LD + ks * 32 + lg * 8);
        a = mfma16(fqh[ks], kbh, a);
        a = mfma16(fqh[ks], kbl, a);
        a = mfma16(fql[ks], kbh, a);
      }
      sa[nf] = a;
    }
    // scale + causal mask (matches ref: exp underflows to exactly 0)
    if (kt == qt) {
#pragma unroll
      for (int nf = 0; nf < 4; nf++) {
        int colg = qt * 64 + nf * 16 + lr;
#pragma unroll
        for (int r = 0; r < 4; r++) {
          float s = sa[nf][r] * 0.125f;
          if (colg > qrow + 4 * lg + r) s = -1e9f;
          sa[nf][r] = s;
        }
      }
    } else {
#pragma unroll
      for (int nf = 0; nf < 4; nf++)
#pragma unroll
        for (int r = 0; r < 4; r++) sa[nf][r] *= 0.125f;
    }
    // online softmax: rows live in 16-lane groups
    float fr[4];
#pragma unroll
    for (int r = 0; r < 4; r++) {
      float mx = fmaxf(fmaxf(sa[0][r], sa[1][r]), fmaxf(sa[2][r], sa[3][r]));
      mx = fmaxf(mx, __shfl_xor(mx, 1));
      mx = fmaxf(mx, __shfl_xor(mx, 2));
      mx = fmaxf(mx, __shfl_xor(mx, 4));
      mx = fmaxf(mx, __shfl_xor(mx, 8));
      float mnew = fmaxf(mrun[r], mx);
      fr[r] = expf(mrun[r] - mnew);
      mrun[r] = mnew;
    }
    float rs[4] = {0.f, 0.f, 0.f, 0.f};
#pragma unroll
    for (int nf = 0; nf < 4; nf++) {
#pragma unroll
      for (int r = 0; r < 4; r++) {
        float p = expf(sa[nf][r] - mrun[r]);
        rs[r] += p;
        ushort h, l; split_hl(p, h, l);
        sPh[wave][(4 * lg + r) * LD + nf * 16 + lr] = h;
        sPl[wave][(4 * lg + r) * LD + nf * 16 + lr] = l;
      }
    }
#pragma unroll
    for (int r = 0; r < 4; r++) {
      float s = rs[r];
      s += __shfl_xor(s, 1); s += __shfl_xor(s, 2);
      s += __shfl_xor(s, 4); s += __shfl_xor(s, 8);
      lrun[r] = lrun[r] * fr[r] + s;
    }
#pragma unroll
    for (int df = 0; df < 4; df++)
#pragma unroll
      for (int r = 0; r < 4; r++) oacc[df][r] *= fr[r];

    // PV (P from per-wave LDS round-trip; V transposed in LDS)
#pragma unroll
    for (int ks = 0; ks < 2; ks++) {
      s16x8 ph = *(const s16x8*)(&sPh[wave][lr * LD + ks * 32 + lg * 8]);
      s16x8 pl = *(const s16x8*)(&sPl[wave][lr * LD + ks * 32 + lg * 8]);
#pragma unroll
      for (int df = 0; df < 4; df++) {
        s16x8 bvh = *(const s16x8*)(sVh + (df * 16 + lr) * LD + ks * 32 + lg * 8);
        s16x8 bvl = *(const s16x8*)(sVl + (df * 16 + lr) * LD + ks * 32 + lg * 8);
        oacc[df] = mfma16(ph, bvh, oacc[df]);
        oacc[df] = mfma16(ph, bvl, oacc[df]);
        oacc[df] = mfma16(pl, bvh, oacc[df]);
      }
    }
    __syncthreads();
  }

  const int b = bh >> 4, h = bh & 15;
#pragma unroll
  for (int r = 0; r < 4; r++) {
    float inv = 1.0f / lrun[r];
    int t = qrow + 4 * lg + r;
#pragma unroll
    for (int df = 0; df < 4; df++) {
      float v = oacc[df][r] * inv;
      ushort hh, ll; split_hl(v, hh, ll);
      size_t idx = ((size_t)(b * TT + t)) * CC + h * 64 + df * 16 + lr;
      att_hi[idx] = hh; att_lo[idx] = ll;
    }
  }
}

extern "C" void kernel_launch(void* const* d_in, const int* in_sizes, int n_in,
                              void* d_out, int out_size, void* d_ws, size_t ws_size,
                              hipStream_t stream) {
  const float* x      = (const float*)d_in[0];
  // d_in[1] = mask: guaranteed causal triu(-1e9); handled analytically
  const float* W_attn = (const float*)d_in[2];
  const float* b_attn = (const float*)d_in[3];
  const float* W_proj = (const float*)d_in[4];
  const float* b_proj = (const float*)d_in[5];
  float* out = (float*)d_out;

  char* w = (char*)d_ws;
  ushort* x_hi  = (ushort*)w; w += (size_t)MM * CC * 2;
  ushort* x_lo  = (ushort*)w; w += (size_t)MM * CC * 2;
  ushort* waT_h = (ushort*)w; w += (size_t)N_QKV * CC * 2;
  ushort* waT_l = (ushort*)w; w += (size_t)N_QKV * CC * 2;
  ushort* wpT_h = (ushort*)w; w += (size_t)CC * CC * 2;
  ushort* wpT_l = (ushort*)w; w += (size_t)CC * CC * 2;
  ushort* q_hi  = (ushort*)w; w += (size_t)MM * CC * 2;
  ushort* q_lo  = (ushort*)w; w += (size_t)MM * CC * 2;
  ushort* att_h = (ushort*)w; w += (size_t)MM * CC * 2;
  ushort* att_l = (ushort*)w; w += (size_t)MM * CC * 2;

  hipLaunchKernelGGL(k_convert, dim3((MM * CC / 8 + 255) / 256), dim3(256), 0, stream,
                     x, x_hi, x_lo, MM * CC / 8);
  hipLaunchKernelGGL(k_transpose_split, dim3(N_QKV / 32, CC / 32), dim3(32, 8), 0, stream,
                     W_attn, waT_h, waT_l, CC, N_QKV);
  hipLaunchKernelGGL(k_transpose_split, dim3(CC / 32, CC / 32), dim3(32, 8), 0, stream,
                     W_proj, wpT_h, wpT_l, CC, CC);
  hipLaunchKernelGGL((k_gemm<0>), dim3(N_QKV / 128, MM / 128), dim3(256), 0, stream,
                     x_hi, x_lo, waT_h, waT_l, b_attn, CC, out, q_hi, q_lo);
  hipLaunchKernelGGL(k_attn, dim3(TT / 64, BB * HH), dim3(256), 0, stream,
                     q_hi, q_lo, out + KSEG, out + VSEG, att_h, att_l);
  hipLaunchKernelGGL((k_gemm<1>), dim3(CC / 128, MM / 128), dim3(256), 0, stream,
                     att_h, att_l, wpT_h, wpT_l, b_proj, CC, out, nullptr, nullptr);
}

// Round 2
// 850.393 us; speedup vs baseline: 1.0968x; 1.0968x over previous
//
#include <hip/hip_runtime.h>
#include <stdint.h>

typedef short  s16x8 __attribute__((ext_vector_type(8)));
typedef ushort u16x8 __attribute__((ext_vector_type(8)));
typedef float  f32x4 __attribute__((ext_vector_type(4)));

constexpr int BB = 4, TT = 2048, CC = 1024, HH = 16, DD = 64;
constexpr int MM = BB * TT;         // 8192
constexpr int N_QKV = 3 * CC;       // 3072
constexpr size_t KSEG = (size_t)MM * CC;   // 8388608
constexpr size_t VSEG = 2 * KSEG;

__device__ __forceinline__ ushort bf16_rne(float f) {
  uint32_t u = __builtin_bit_cast(uint32_t, f);
  u += 0x7fffu + ((u >> 16) & 1u);
  return (ushort)(u >> 16);
}
__device__ __forceinline__ float bf16_to_f32(ushort h) {
  uint32_t u = ((uint32_t)h) << 16;
  return __builtin_bit_cast(float, u);
}
__device__ __forceinline__ void split_hl(float f, ushort &hi, ushort &lo) {
  hi = bf16_rne(f);
  lo = bf16_rne(f - bf16_to_f32(hi));
}
__device__ __forceinline__ f32x4 mfma16(s16x8 a, s16x8 b, f32x4 c) {
  return __builtin_amdgcn_mfma_f32_16x16x32_bf16(a, b, c, 0, 0, 0);
}

// ---------------- split convert: f32 -> bf16 hi/lo ----------------
__global__ void k_convert(const float* __restrict__ src, ushort* __restrict__ hi,
                          ushort* __restrict__ lo, int n8) {
  int i = blockIdx.x * blockDim.x + threadIdx.x;
  if (i >= n8) return;
  float4 a = ((const float4*)src)[2 * i];
  float4 b = ((const float4*)src)[2 * i + 1];
  float f[8] = {a.x, a.y, a.z, a.w, b.x, b.y, b.z, b.w};
  u16x8 h, l;
#pragma unroll
  for (int j = 0; j < 8; j++) { ushort hh, ll; split_hl(f[j], hh, ll); h[j] = hh; l[j] = ll; }
  *(u16x8*)(hi + 8 * (size_t)i) = h;
  *(u16x8*)(lo + 8 * (size_t)i) = l;
}

// ------------- transpose + split: W[K][N] -> T[N][K] bf16 hi/lo -------------
__global__ void k_transpose_split(const float* __restrict__ W, ushort* __restrict__ Th,
                                  ushort* __restrict__ Tl, int K, int N) {
  __shared__ float tile[32][33];
  int nt = blockIdx.x * 32, kt = blockIdx.y * 32;
  int tx = threadIdx.x, ty = threadIdx.y;
#pragma unroll
  for (int i = 0; i < 4; i++)
    tile[ty + i * 8][tx] = W[(size_t)(kt + ty + i * 8) * N + nt + tx];
  __syncthreads();
#pragma unroll
  for (int i = 0; i < 4; i++) {
    int nl = ty + i * 8;
    float f = tile[tx][nl];
    ushort h, l; split_hl(f, h, l);
    size_t o = (size_t)(nt + nl) * K + kt + tx;
    Th[o] = h; Tl[o] = l;
  }
}

// ---------------- GEMM: C[M][N] = A[M][K] * Bt[N][K]^T + bias ----------------
// bf16x3: 3 MFMAs per (hi,lo) operand pair. 128x128 tile, BK=32, 4 waves (2x2 of 64x64).
// MODE 0: QKV epilogue: q (pre-scaled 1/8) -> hi/lo ws; k -> f32 d_out + hi/lo ws;
//         v -> f32 d_out + hi/lo ws TRANSPOSED [bh][d][t].
// MODE 1: plain f32 out[m*CC + n]
template<int MODE>
__global__ __launch_bounds__(256) void k_gemm(
    const ushort* __restrict__ Ah, const ushort* __restrict__ Al,
    const ushort* __restrict__ Bth, const ushort* __restrict__ Btl,
    const float* __restrict__ bias, int K,
    float* __restrict__ outF, ushort* __restrict__ q_hi, ushort* __restrict__ q_lo,
    ushort* __restrict__ kh, ushort* __restrict__ kl,
    ushort* __restrict__ vth, ushort* __restrict__ vtl) {
  constexpr int LDK = 40;  // 32 + 8 pad
  __shared__ ushort sAh[128 * LDK], sAl[128 * LDK], sBh[128 * LDK], sBl[128 * LDK];
  const int tid = threadIdx.x;
  const int wave = tid >> 6, lane = tid & 63;
  const int wr = wave >> 1, wc = wave & 1;
  const int lr = lane & 15, lg = lane >> 4;
  const int m0 = blockIdx.y * 128, n0 = blockIdx.x * 128;
  const int srow = tid >> 2;
  const int sk = (tid & 3) * 8;

  f32x4 acc[4][4] = {};

  for (int kt = 0; kt < K; kt += 32) {
#pragma unroll
    for (int p = 0; p < 2; p++) {
      int row = srow + p * 64;
      size_t ga = (size_t)(m0 + row) * K + kt + sk;
      size_t gb = (size_t)(n0 + row) * K + kt + sk;
      *(u16x8*)(sAh + row * LDK + sk) = *(const u16x8*)(Ah + ga);
      *(u16x8*)(sAl + row * LDK + sk) = *(const u16x8*)(Al + ga);
      *(u16x8*)(sBh + row * LDK + sk) = *(const u16x8*)(Bth + gb);
      *(u16x8*)(sBl + row * LDK + sk) = *(const u16x8*)(Btl + gb);
    }
    __syncthreads();
    s16x8 fah[4], fal[4], fbh[4], fbl[4];
#pragma unroll
    for (int i = 0; i < 4; i++) {
      fah[i] = *(const s16x8*)(sAh + (wr * 64 + i * 16 + lr) * LDK + lg * 8);
      fal[i] = *(const s16x8*)(sAl + (wr * 64 + i * 16 + lr) * LDK + lg * 8);
      fbh[i] = *(const s16x8*)(sBh + (wc * 64 + i * 16 + lr) * LDK + lg * 8);
      fbl[i] = *(const s16x8*)(sBl + (wc * 64 + i * 16 + lr) * LDK + lg * 8);
    }
#pragma unroll
    for (int mf = 0; mf < 4; mf++)
#pragma unroll
      for (int nf = 0; nf < 4; nf++) {
        acc[mf][nf] = mfma16(fah[mf], fbh[nf], acc[mf][nf]);
        acc[mf][nf] = mfma16(fah[mf], fbl[nf], acc[mf][nf]);
        acc[mf][nf] = mfma16(fal[mf], fbh[nf], acc[mf][nf]);
      }
    __syncthreads();
  }

#pragma unroll
  for (int mf = 0; mf < 4; mf++) {
#pragma unroll
    for (int nf = 0; nf < 4; nf++) {
      int n = n0 + wc * 64 + nf * 16 + lr;
      float bv = bias[n];
#pragma unroll
      for (int r = 0; r < 4; r++) {
        int m = m0 + wr * 64 + mf * 16 + lg * 4 + r;
        float v = acc[mf][nf][r] + bv;
        if constexpr (MODE == 0) {
          int b = m >> 11, t = m & 2047;
          int seg = n >> 10, nn = n & 1023;
          int h = nn >> 6, d = nn & 63;
          size_t idx = ((size_t)((b * 16 + h) * 2048 + t)) * 64 + d;
          if (seg == 0) {
            ushort hh, ll; split_hl(v * 0.125f, hh, ll);
            q_hi[idx] = hh; q_lo[idx] = ll;
          } else if (seg == 1) {
            outF[KSEG + idx] = v;
            ushort hh, ll; split_hl(v, hh, ll);
            kh[idx] = hh; kl[idx] = ll;
          } else {
            outF[VSEG + idx] = v;
            ushort hh, ll; split_hl(v, hh, ll);
            size_t vidx = ((size_t)((b * 16 + h) * 64 + d)) * 2048 + t;
            vth[vidx] = hh; vtl[vidx] = ll;
          }
        } else {
          outF[(size_t)m * CC + n] = v;
        }
      }
    }
  }
}

// ---------------- flash attention (causal) ----------------
// grid: (T/64 q-tiles, B*H). 4 waves x 16 q-rows. KV tiles of 64.
// K,V pre-converted bf16 hi/lo in ws (V pre-transposed [bh][d][t]).
// P aliases the K LDS buffers (K dead after QK^T; extra barrier).
__global__ __launch_bounds__(256) void k_attn(
    const ushort* __restrict__ q_hi, const ushort* __restrict__ q_lo,
    const ushort* __restrict__ kh, const ushort* __restrict__ kl,
    const ushort* __restrict__ vth, const ushort* __restrict__ vtl,
    ushort* __restrict__ att_hi, ushort* __restrict__ att_lo) {
  constexpr int LD = 72;  // 64 + 8 pad (144 B rows, 16B aligned)
  __shared__ ushort sK0[64 * LD], sK1[64 * LD];  // K hi/lo; aliased as P hi/lo
  __shared__ ushort sV0[64 * LD], sV1[64 * LD];  // V^T hi/lo: [d][kv]
  const int tid = threadIdx.x, wave = tid >> 6, lane = tid & 63;
  const int lr = lane & 15, lg = lane >> 4;
  const int qt = blockIdx.x, bh = blockIdx.y;
  const int qrow = qt * 64 + wave * 16;

  // hoist Q fragments (pre-scaled by 1/8 in the QKV epilogue)
  s16x8 fqh[2], fql[2];
  {
    size_t qb = ((size_t)bh * TT + qrow + lr) * 64;
#pragma unroll
    for (int ks = 0; ks < 2; ks++) {
      fqh[ks] = *(const s16x8*)(q_hi + qb + ks * 32 + lg * 8);
      fql[ks] = *(const s16x8*)(q_lo + qb + ks * 32 + lg * 8);
    }
  }
  float mrun[4], lrun[4];
#pragma unroll
  for (int r = 0; r < 4; r++) { mrun[r] = -INFINITY; lrun[r] = 0.f; }
  f32x4 oacc[4] = {};

  ushort* const Pb0 = sK0 + wave * 16 * LD;  // per-wave P region (aliases K)
  ushort* const Pb1 = sK1 + wave * 16 * LD;

  for (int kt = 0; kt <= qt; kt++) {
    // --- stage: pure vectorized u16x8 copies, no conversion ---
#pragma unroll
    for (int it = 0; it < 2; it++) {
      int vv = tid + it * 256;
      int row = vv >> 3, c8 = (vv & 7) * 8;
      size_t gk = ((size_t)bh * TT + kt * 64 + row) * 64 + c8;
      size_t gv = ((size_t)bh * 64 + row) * TT + kt * 64 + c8;
      *(u16x8*)(sK0 + row * LD + c8) = *(const u16x8*)(kh + gk);
      *(u16x8*)(sK1 + row * LD + c8) = *(const u16x8*)(kl + gk);
      *(u16x8*)(sV0 + row * LD + c8) = *(const u16x8*)(vth + gv);
      *(u16x8*)(sV1 + row * LD + c8) = *(const u16x8*)(vtl + gv);
    }
    __syncthreads();

    // --- S = Q K^T (bf16x3, scale pre-folded into q) ---
    f32x4 sa[4];
#pragma unroll
    for (int nf = 0; nf < 4; nf++) {
      f32x4 a = {};
#pragma unroll
      for (int ks = 0; ks < 2; ks++) {
        s16x8 kbh = *(const s16x8*)(sK0 + (nf * 16 + lr) * LD + ks * 32 + lg * 8);
        s16x8 kbl = *(const s16x8*)(sK1 + (nf * 16 + lr) * LD + ks * 32 + lg * 8);
        a = mfma16(fqh[ks], kbh, a);
        a = mfma16(fqh[ks], kbl, a);
        a = mfma16(fql[ks], kbh, a);
      }
      sa[nf] = a;
    }
    // causal mask on the diagonal tile
    if (kt == qt) {
#pragma unroll
      for (int nf = 0; nf < 4; nf++) {
        int colg = qt * 64 + nf * 16 + lr;
#pragma unroll
        for (int r = 0; r < 4; r++)
          if (colg > qrow + 4 * lg + r) sa[nf][r] = -1e9f;
      }
    }
    // --- online softmax (rows live across 16-lane groups) ---
    float fr[4];
#pragma unroll
    for (int r = 0; r < 4; r++) {
      float mx = fmaxf(fmaxf(sa[0][r], sa[1][r]), fmaxf(sa[2][r], sa[3][r]));
      mx = fmaxf(mx, __shfl_xor(mx, 1));
      mx = fmaxf(mx, __shfl_xor(mx, 2));
      mx = fmaxf(mx, __shfl_xor(mx, 4));
      mx = fmaxf(mx, __shfl_xor(mx, 8));
      float mnew = fmaxf(mrun[r], mx);
      fr[r] = __expf(mrun[r] - mnew);
      mrun[r] = mnew;
    }
    __syncthreads();  // all waves done reading K before P overwrites it
    float rs[4] = {0.f, 0.f, 0.f, 0.f};
#pragma unroll
    for (int nf = 0; nf < 4; nf++) {
#pragma unroll
      for (int r = 0; r < 4; r++) {
        float p = __expf(sa[nf][r] - mrun[r]);
        rs[r] += p;
        ushort h, l; split_hl(p, h, l);
        Pb0[(4 * lg + r) * LD + nf * 16 + lr] = h;
        Pb1[(4 * lg + r) * LD + nf * 16 + lr] = l;
      }
    }
#pragma unroll
    for (int r = 0; r < 4; r++) {
      float s = rs[r];
      s += __shfl_xor(s, 1); s += __shfl_xor(s, 2);
      s += __shfl_xor(s, 4); s += __shfl_xor(s, 8);
      lrun[r] = lrun[r] * fr[r] + s;
    }
#pragma unroll
    for (int df = 0; df < 4; df++)
#pragma unroll
      for (int r = 0; r < 4; r++) oacc[df][r] *= fr[r];

    // --- PV: P (own wave region) x V^T tiles ---
#pragma unroll
    for (int ks = 0; ks < 2; ks++) {
      s16x8 ph = *(const s16x8*)(Pb0 + lr * LD + ks * 32 + lg * 8);
      s16x8 pl = *(const s16x8*)(Pb1 + lr * LD + ks * 32 + lg * 8);
#pragma unroll
      for (int df = 0; df < 4; df++) {
        s16x8 bvh = *(const s16x8*)(sV0 + (df * 16 + lr) * LD + ks * 32 + lg * 8);
        s16x8 bvl = *(const s16x8*)(sV1 + (df * 16 + lr) * LD + ks * 32 + lg * 8);
        oacc[df] = mfma16(ph, bvh, oacc[df]);
        oacc[df] = mfma16(ph, bvl, oacc[df]);
        oacc[df] = mfma16(pl, bvh, oacc[df]);
      }
    }
    __syncthreads();  // P + V^T consumed before next stage overwrites
  }

  const int b = bh >> 4, h = bh & 15;
#pragma unroll
  for (int r = 0; r < 4; r++) {
    float inv = 1.0f / lrun[r];
    int t = qrow + 4 * lg + r;
#pragma unroll
    for (int df = 0; df < 4; df++) {
      float v = oacc[df][r] * inv;
      ushort hh, ll; split_hl(v, hh, ll);
      size_t idx = ((size_t)(b * TT + t)) * CC + h * 64 + df * 16 + lr;
      att_hi[idx] = hh; att_lo[idx] = ll;
    }
  }
}

extern "C" void kernel_launch(void* const* d_in, const int* in_sizes, int n_in,
                              void* d_out, int out_size, void* d_ws, size_t ws_size,
                              hipStream_t stream) {
  const float* x      = (const float*)d_in[0];
  // d_in[1] = mask: causal triu(-1e9); handled analytically
  const float* W_attn = (const float*)d_in[2];
  const float* b_attn = (const float*)d_in[3];
  const float* W_proj = (const float*)d_in[4];
  const float* b_proj = (const float*)d_in[5];
  float* out = (float*)d_out;

  char* w = (char*)d_ws;
  ushort* x_hi  = (ushort*)w; w += (size_t)MM * CC * 2;      // aliased as att_hi after x consumed
  ushort* x_lo  = (ushort*)w; w += (size_t)MM * CC * 2;      // aliased as att_lo
  ushort* waT_h = (ushort*)w; w += (size_t)N_QKV * CC * 2;
  ushort* waT_l = (ushort*)w; w += (size_t)N_QKV * CC * 2;
  ushort* wpT_h = (ushort*)w; w += (size_t)CC * CC * 2;
  ushort* wpT_l = (ushort*)w; w += (size_t)CC * CC * 2;
  ushort* q_hi  = (ushort*)w; w += (size_t)MM * CC * 2;
  ushort* q_lo  = (ushort*)w; w += (size_t)MM * CC * 2;
  ushort* k_hi  = (ushort*)w; w += (size_t)MM * CC * 2;
  ushort* k_lo  = (ushort*)w; w += (size_t)MM * CC * 2;
  ushort* vT_hi = (ushort*)w; w += (size_t)MM * CC * 2;
  ushort* vT_lo = (ushort*)w; w += (size_t)MM * CC * 2;
  ushort* att_h = x_hi;  // x fully consumed by k_gemm<0> before k_attn writes here
  ushort* att_l = x_lo;

  hipLaunchKernelGGL(k_convert, dim3((MM * CC / 8 + 255) / 256), dim3(256), 0, stream,
                     x, x_hi, x_lo, MM * CC / 8);
  hipLaunchKernelGGL(k_transpose_split, dim3(N_QKV / 32, CC / 32), dim3(32, 8), 0, stream,
                     W_attn, waT_h, waT_l, CC, N_QKV);
  hipLaunchKernelGGL(k_transpose_split, dim3(CC / 32, CC / 32), dim3(32, 8), 0, stream,
                     W_proj, wpT_h, wpT_l, CC, CC);
  hipLaunchKernelGGL((k_gemm<0>), dim3(N_QKV / 128, MM / 128), dim3(256), 0, stream,
                     x_hi, x_lo, waT_h, waT_l, b_attn, CC, out, q_hi, q_lo,
                     k_hi, k_lo, vT_hi, vT_lo);
  hipLaunchKernelGGL(k_attn, dim3(TT / 64, BB * HH), dim3(256), 0, stream,
                     q_hi, q_lo, k_hi, k_lo, vT_hi, vT_lo, att_h, att_l);
  hipLaunchKernelGGL((k_gemm<1>), dim3(CC / 128, MM / 128), dim3(256), 0, stream,
                     att_h, att_l, wpT_h, wpT_l, b_proj, CC, out,
                     nullptr, nullptr, nullptr, nullptr, nullptr, nullptr);
}

// Round 4
// 738.896 us; speedup vs baseline: 1.2623x; 1.1509x over previous
//
#include <hip/hip_runtime.h>
#include <stdint.h>

typedef short  s16x8 __attribute__((ext_vector_type(8)));
typedef ushort u16x8 __attribute__((ext_vector_type(8)));
typedef float  f32x4 __attribute__((ext_vector_type(4)));

constexpr int BB = 4, TT = 2048, CC = 1024, HH = 16, DD = 64;
constexpr int MM = BB * TT;         // 8192
constexpr int N_QKV = 3 * CC;       // 3072
constexpr size_t KSEG = (size_t)MM * CC;   // 8388608
constexpr size_t VSEG = 2 * KSEG;

// XOR swizzle, ushort units. Rows of 64 ushorts (128B): slot = 8 ushorts (16B).
#define SWZ64(row, uoff) ((row) * 64 + ((uoff) ^ (((row) & 7) << 3)))
// Rows of 32 ushorts (64B) for GEMM tiles.
#define SWZ32(row, uoff) ((row) * 32 + ((uoff) ^ (((row) & 3) << 3)))

__device__ __forceinline__ ushort bf16_rne(float f) {
  uint32_t u = __builtin_bit_cast(uint32_t, f);
  u += 0x7fffu + ((u >> 16) & 1u);
  return (ushort)(u >> 16);
}
__device__ __forceinline__ float bf16_to_f32(ushort h) {
  uint32_t u = ((uint32_t)h) << 16;
  return __builtin_bit_cast(float, u);
}
__device__ __forceinline__ void split_hl(float f, ushort &hi, ushort &lo) {
  hi = bf16_rne(f);
  lo = bf16_rne(f - bf16_to_f32(hi));
}
__device__ __forceinline__ f32x4 mfma16(s16x8 a, s16x8 b, f32x4 c) {
  return __builtin_amdgcn_mfma_f32_16x16x32_bf16(a, b, c, 0, 0, 0);
}

// ---------------- split convert: f32 -> bf16 hi/lo ----------------
__global__ void k_convert(const float* __restrict__ src, ushort* __restrict__ hi,
                          ushort* __restrict__ lo, int n8) {
  int i = blockIdx.x * blockDim.x + threadIdx.x;
  if (i >= n8) return;
  float4 a = ((const float4*)src)[2 * i];
  float4 b = ((const float4*)src)[2 * i + 1];
  float f[8] = {a.x, a.y, a.z, a.w, b.x, b.y, b.z, b.w};
  u16x8 h, l;
#pragma unroll
  for (int j = 0; j < 8; j++) { ushort hh, ll; split_hl(f[j], hh, ll); h[j] = hh; l[j] = ll; }
  *(u16x8*)(hi + 8 * (size_t)i) = h;
  *(u16x8*)(lo + 8 * (size_t)i) = l;
}

// ------------- transpose + split: W[K][N] -> T[N][K] bf16 hi/lo -------------
__global__ void k_transpose_split(const float* __restrict__ W, ushort* __restrict__ Th,
                                  ushort* __restrict__ Tl, int K, int N) {
  __shared__ float tile[32][33];
  int nt = blockIdx.x * 32, kt = blockIdx.y * 32;
  int tx = threadIdx.x, ty = threadIdx.y;
#pragma unroll
  for (int i = 0; i < 4; i++)
    tile[ty + i * 8][tx] = W[(size_t)(kt + ty + i * 8) * N + nt + tx];
  __syncthreads();
#pragma unroll
  for (int i = 0; i < 4; i++) {
    int nl = ty + i * 8;
    float f = tile[tx][nl];
    ushort h, l; split_hl(f, h, l);
    size_t o = (size_t)(nt + nl) * K + kt + tx;
    Th[o] = h; Tl[o] = l;
  }
}

// ---------------- GEMM: C[M][N] = A[M][K] * Bt[N][K]^T + bias ----------------
// bf16x3. 128x128 tile, BK=32, 4 waves (2x2 of 64x64). XOR-swizzled LDS (no pad).
template<int MODE>
__global__ __launch_bounds__(256) void k_gemm(
    const ushort* __restrict__ Ah, const ushort* __restrict__ Al,
    const ushort* __restrict__ Bth, const ushort* __restrict__ Btl,
    const float* __restrict__ bias, int K,
    float* __restrict__ outF, ushort* __restrict__ q_hi, ushort* __restrict__ q_lo,
    ushort* __restrict__ kh, ushort* __restrict__ kl,
    ushort* __restrict__ vth, ushort* __restrict__ vtl) {
  __shared__ ushort sAh[128 * 32], sAl[128 * 32], sBh[128 * 32], sBl[128 * 32];
  const int tid = threadIdx.x;
  const int wave = tid >> 6, lane = tid & 63;
  const int wr = wave >> 1, wc = wave & 1;
  const int lr = lane & 15, lg = lane >> 4;
  const int m0 = blockIdx.y * 128, n0 = blockIdx.x * 128;
  const int srow = tid >> 2;
  const int sk = (tid & 3) * 8;

  f32x4 acc[4][4] = {};

  for (int kt = 0; kt < K; kt += 32) {
#pragma unroll
    for (int p = 0; p < 2; p++) {
      int row = srow + p * 64;
      size_t ga = (size_t)(m0 + row) * K + kt + sk;
      size_t gb = (size_t)(n0 + row) * K + kt + sk;
      int d = SWZ32(row, sk);
      *(u16x8*)(sAh + d) = *(const u16x8*)(Ah + ga);
      *(u16x8*)(sAl + d) = *(const u16x8*)(Al + ga);
      *(u16x8*)(sBh + d) = *(const u16x8*)(Bth + gb);
      *(u16x8*)(sBl + d) = *(const u16x8*)(Btl + gb);
    }
    __syncthreads();
    s16x8 fah[4], fal[4], fbh[4], fbl[4];
#pragma unroll
    for (int i = 0; i < 4; i++) {
      int ra = wr * 64 + i * 16 + lr, rb = wc * 64 + i * 16 + lr;
      fah[i] = *(const s16x8*)(sAh + SWZ32(ra, lg * 8));
      fal[i] = *(const s16x8*)(sAl + SWZ32(ra, lg * 8));
      fbh[i] = *(const s16x8*)(sBh + SWZ32(rb, lg * 8));
      fbl[i] = *(const s16x8*)(sBl + SWZ32(rb, lg * 8));
    }
#pragma unroll
    for (int mf = 0; mf < 4; mf++)
#pragma unroll
      for (int nf = 0; nf < 4; nf++) {
        acc[mf][nf] = mfma16(fah[mf], fbh[nf], acc[mf][nf]);
        acc[mf][nf] = mfma16(fah[mf], fbl[nf], acc[mf][nf]);
        acc[mf][nf] = mfma16(fal[mf], fbh[nf], acc[mf][nf]);
      }
    __syncthreads();
  }

#pragma unroll
  for (int mf = 0; mf < 4; mf++) {
#pragma unroll
    for (int nf = 0; nf < 4; nf++) {
      int n = n0 + wc * 64 + nf * 16 + lr;
      float bv = bias[n];
#pragma unroll
      for (int r = 0; r < 4; r++) {
        int m = m0 + wr * 64 + mf * 16 + lg * 4 + r;
        float v = acc[mf][nf][r] + bv;
        if constexpr (MODE == 0) {
          int b = m >> 11, t = m & 2047;
          int seg = n >> 10, nn = n & 1023;
          int h = nn >> 6, d = nn & 63;
          size_t idx = ((size_t)((b * 16 + h) * 2048 + t)) * 64 + d;
          if (seg == 0) {
            ushort hh, ll; split_hl(v * 0.125f, hh, ll);
            q_hi[idx] = hh; q_lo[idx] = ll;
          } else if (seg == 1) {
            outF[KSEG + idx] = v;
            ushort hh, ll; split_hl(v, hh, ll);
            kh[idx] = hh; kl[idx] = ll;
          } else {
            outF[VSEG + idx] = v;
            ushort hh, ll; split_hl(v, hh, ll);
            size_t vidx = ((size_t)((b * 16 + h) * 64 + d)) * 2048 + t;
            vth[vidx] = hh; vtl[vidx] = ll;
          }
        } else {
          outF[(size_t)m * CC + n] = v;
        }
      }
    }
  }
}

// ---------------- flash attention (causal, paired q-tiles) ----------------
// grid: (16 q-tile pairs, B*H). Block px handles q-tiles qa=px and qb=31-px,
// sharing each staged K/V tile. 4 waves x 16 q-rows per tile. KV tile 64.
// XOR-swizzled LDS; per-wave private P buffers -> only 2 barriers per KV tile.
__global__ __launch_bounds__(256, 3) void k_attn(
    const ushort* __restrict__ q_hi, const ushort* __restrict__ q_lo,
    const ushort* __restrict__ kh, const ushort* __restrict__ kl,
    const ushort* __restrict__ vth, const ushort* __restrict__ vtl,
    ushort* __restrict__ att_hi, ushort* __restrict__ att_lo) {
  __shared__ ushort sK0[64 * 64], sK1[64 * 64];   // K hi/lo, swizzled rows
  __shared__ ushort sV0[64 * 64], sV1[64 * 64];   // V^T hi/lo: [d][kv]
  __shared__ ushort sP0[4][16 * 64], sP1[4][16 * 64];  // per-wave P hi/lo
  const int tid = threadIdx.x, wave = tid >> 6, lane = tid & 63;
  const int lr = lane & 15, lg = lane >> 4;
  const int px = blockIdx.x, bh = blockIdx.y;
  const int qa = px, qb = 31 - px;
  const int qrow_a = qa * 64 + wave * 16;
  const int qrow_b = qb * 64 + wave * 16;

  // hoist Q fragments for both tiles (q pre-scaled by 1/8 in QKV epilogue)
  s16x8 fqah[2], fqal[2], fqbh[2], fqbl[2];
  {
    size_t ba = ((size_t)bh * TT + qrow_a + lr) * 64;
    size_t bb = ((size_t)bh * TT + qrow_b + lr) * 64;
#pragma unroll
    for (int ks = 0; ks < 2; ks++) {
      fqah[ks] = *(const s16x8*)(q_hi + ba + ks * 32 + lg * 8);
      fqal[ks] = *(const s16x8*)(q_lo + ba + ks * 32 + lg * 8);
      fqbh[ks] = *(const s16x8*)(q_hi + bb + ks * 32 + lg * 8);
      fqbl[ks] = *(const s16x8*)(q_lo + bb + ks * 32 + lg * 8);
    }
  }
  float mra[4], lra[4], mrb[4], lrb[4];
#pragma unroll
  for (int r = 0; r < 4; r++) { mra[r] = -INFINITY; lra[r] = 0.f; mrb[r] = -INFINITY; lrb[r] = 0.f; }
  f32x4 oa[4] = {}, ob[4] = {};

  // one K/V tile step for one q-tile: QK^T -> online softmax -> P -> PV
  auto tile_step = [&](const s16x8* fqh, const s16x8* fql, float* mrun, float* lrun,
                       f32x4* oacc, bool diag) {
    f32x4 sa[4];
#pragma unroll
    for (int nf = 0; nf < 4; nf++) {
      f32x4 a = {};
#pragma unroll
      for (int ks = 0; ks < 2; ks++) {
        int d = SWZ64(nf * 16 + lr, ks * 32 + lg * 8);
        s16x8 kbh = *(const s16x8*)(sK0 + d);
        s16x8 kbl = *(const s16x8*)(sK1 + d);
        a = mfma16(fqh[ks], kbh, a);
        a = mfma16(fqh[ks], kbl, a);
        a = mfma16(fql[ks], kbh, a);
      }
      sa[nf] = a;
    }
    if (diag) {
#pragma unroll
      for (int nf = 0; nf < 4; nf++) {
        int col = nf * 16 + lr;
#pragma unroll
        for (int r = 0; r < 4; r++)
          if (col > wave * 16 + 4 * lg + r) sa[nf][r] = -1e9f;
      }
    }
    // row max of this tile
    float mx[4];
#pragma unroll
    for (int r = 0; r < 4; r++) {
      float m = fmaxf(fmaxf(sa[0][r], sa[1][r]), fmaxf(sa[2][r], sa[3][r]));
      m = fmaxf(m, __shfl_xor(m, 1));
      m = fmaxf(m, __shfl_xor(m, 2));
      m = fmaxf(m, __shfl_xor(m, 4));
      m = fmaxf(m, __shfl_xor(m, 8));
      mx[r] = m;
    }
    // defer-max: only rescale when max grew by > 8 (P bounded by e^8 otherwise)
    int grow = 0;
#pragma unroll
    for (int r = 0; r < 4; r++) grow |= (mx[r] > mrun[r] + 8.0f);
    if (__any(grow)) {
#pragma unroll
      for (int r = 0; r < 4; r++) {
        float mnew = fmaxf(mrun[r], mx[r]);
        float fr = __expf(mrun[r] - mnew);
        mrun[r] = mnew;
        lrun[r] *= fr;
#pragma unroll
        for (int df = 0; df < 4; df++) oacc[df][r] *= fr;
      }
    }
    // P = exp(S - m), write bf16 hi/lo to this wave's private P buffer
    float rs[4] = {0.f, 0.f, 0.f, 0.f};
    ushort* Pb0 = sP0[wave];
    ushort* Pb1 = sP1[wave];
#pragma unroll
    for (int nf = 0; nf < 4; nf++) {
#pragma unroll
      for (int r = 0; r < 4; r++) {
        float p = __expf(sa[nf][r] - mrun[r]);
        rs[r] += p;
        ushort h, l; split_hl(p, h, l);
        int d = SWZ64(4 * lg + r, nf * 16 + lr);
        Pb0[d] = h; Pb1[d] = l;
      }
    }
#pragma unroll
    for (int r = 0; r < 4; r++) {
      float s = rs[r];
      s += __shfl_xor(s, 1); s += __shfl_xor(s, 2);
      s += __shfl_xor(s, 4); s += __shfl_xor(s, 8);
      lrun[r] += s;
    }
    // PV: P (private region) x V^T
#pragma unroll
    for (int ks = 0; ks < 2; ks++) {
      int dp = SWZ64(lr, ks * 32 + lg * 8);
      s16x8 ph = *(const s16x8*)(Pb0 + dp);
      s16x8 pl = *(const s16x8*)(Pb1 + dp);
#pragma unroll
      for (int df = 0; df < 4; df++) {
        int dv = SWZ64(df * 16 + lr, ks * 32 + lg * 8);
        s16x8 bvh = *(const s16x8*)(sV0 + dv);
        s16x8 bvl = *(const s16x8*)(sV1 + dv);
        oacc[df] = mfma16(ph, bvh, oacc[df]);
        oacc[df] = mfma16(ph, bvl, oacc[df]);
        oacc[df] = mfma16(pl, bvh, oacc[df]);
      }
    }
  };

  for (int kt = 0; kt <= qb; kt++) {
    // stage K (row-major) and V^T (pre-transposed), vectorized swizzled copies
#pragma unroll
    for (int it = 0; it < 2; it++) {
      int vv = tid + it * 256;
      int row = vv >> 3, cu = (vv & 7) * 8;
      size_t gk = ((size_t)bh * TT + kt * 64 + row) * 64 + cu;
      size_t gv = ((size_t)bh * 64 + row) * TT + kt * 64 + cu;
      int d = SWZ64(row, cu);
      *(u16x8*)(sK0 + d) = *(const u16x8*)(kh + gk);
      *(u16x8*)(sK1 + d) = *(const u16x8*)(kl + gk);
      *(u16x8*)(sV0 + d) = *(const u16x8*)(vth + gv);
      *(u16x8*)(sV1 + d) = *(const u16x8*)(vtl + gv);
    }
    __syncthreads();
    if (kt <= qa) tile_step(fqah, fqal, mra, lra, oa, kt == qa);
    tile_step(fqbh, fqbl, mrb, lrb, ob, kt == qb);
    __syncthreads();
  }

  const int b = bh >> 4, h = bh & 15;
#pragma unroll
  for (int r = 0; r < 4; r++) {
    float inva = 1.0f / lra[r], invb = 1.0f / lrb[r];
    int ta = qrow_a + 4 * lg + r, tb = qrow_b + 4 * lg + r;
#pragma unroll
    for (int df = 0; df < 4; df++) {
      float va = oa[df][r] * inva, vb = ob[df][r] * invb;
      ushort hh, ll;
      size_t ia = ((size_t)(b * TT + ta)) * CC + h * 64 + df * 16 + lr;
      size_t ib = ((size_t)(b * TT + tb)) * CC + h * 64 + df * 16 + lr;
      split_hl(va, hh, ll); att_hi[ia] = hh; att_lo[ia] = ll;
      split_hl(vb, hh, ll); att_hi[ib] = hh; att_lo[ib] = ll;
    }
  }
}

extern "C" void kernel_launch(void* const* d_in, const int* in_sizes, int n_in,
                              void* d_out, int out_size, void* d_ws, size_t ws_size,
                              hipStream_t stream) {
  const float* x      = (const float*)d_in[0];
  // d_in[1] = mask: causal triu(-1e9); handled analytically
  const float* W_attn = (const float*)d_in[2];
  const float* b_attn = (const float*)d_in[3];
  const float* W_proj = (const float*)d_in[4];
  const float* b_proj = (const float*)d_in[5];
  float* out = (float*)d_out;

  char* w = (char*)d_ws;
  ushort* x_hi  = (ushort*)w; w += (size_t)MM * CC * 2;   // aliased as att_hi after x consumed
  ushort* x_lo  = (ushort*)w; w += (size_t)MM * CC * 2;   // aliased as att_lo
  ushort* waT_h = (ushort*)w; w += (size_t)N_QKV * CC * 2;
  ushort* waT_l = (ushort*)w; w += (size_t)N_QKV * CC * 2;
  ushort* wpT_h = (ushort*)w; w += (size_t)CC * CC * 2;
  ushort* wpT_l = (ushort*)w; w += (size_t)CC * CC * 2;
  ushort* q_hi  = (ushort*)w; w += (size_t)MM * CC * 2;
  ushort* q_lo  = (ushort*)w; w += (size_t)MM * CC * 2;
  ushort* k_hi  = (ushort*)w; w += (size_t)MM * CC * 2;
  ushort* k_lo  = (ushort*)w; w += (size_t)MM * CC * 2;
  ushort* vT_hi = (ushort*)w; w += (size_t)MM * CC * 2;
  ushort* vT_lo = (ushort*)w; w += (size_t)MM * CC * 2;
  ushort* att_h = x_hi;  // x fully consumed by k_gemm<0> before k_attn writes here
  ushort* att_l = x_lo;

  hipLaunchKernelGGL(k_convert, dim3((MM * CC / 8 + 255) / 256), dim3(256), 0, stream,
                     x, x_hi, x_lo, MM * CC / 8);
  hipLaunchKernelGGL(k_transpose_split, dim3(N_QKV / 32, CC / 32), dim3(32, 8), 0, stream,
                     W_attn, waT_h, waT_l, CC, N_QKV);
  hipLaunchKernelGGL(k_transpose_split, dim3(CC / 32, CC / 32), dim3(32, 8), 0, stream,
                     W_proj, wpT_h, wpT_l, CC, CC);
  hipLaunchKernelGGL((k_gemm<0>), dim3(N_QKV / 128, MM / 128), dim3(256), 0, stream,
                     x_hi, x_lo, waT_h, waT_l, b_attn, CC, out, q_hi, q_lo,
                     k_hi, k_lo, vT_hi, vT_lo);
  hipLaunchKernelGGL(k_attn, dim3(16, BB * HH), dim3(256), 0, stream,
                     q_hi, q_lo, k_hi, k_lo, vT_hi, vT_lo, att_h, att_l);
  hipLaunchKernelGGL((k_gemm<1>), dim3(CC / 128, MM / 128), dim3(256), 0, stream,
                     att_h, att_l, wpT_h, wpT_l, b_proj, CC, out,
                     nullptr, nullptr, nullptr, nullptr, nullptr, nullptr);
}